// Round 3
// baseline (253.467 us; speedup 1.0000x reference)
//
#include <hip/hip_runtime.h>
#include <hip/hip_bf16.h>

// SparseLoRAMoE: out[t,d] = 2 * sum_k routing[t,k] *
//                 sum_r silu(dot(x[t,:], w_a[e_k,r,:])) * w_b[e_k,d,r]
// B=2,S=2048 -> 4096 tokens; D_IN=D_OUT=2048; E=16; R=16; K=2. fp32.
//
// Round 3: expert-PAIR bucketing. Tokens are bucketed by ordered pair
// (e0,e1) -> 256 buckets (~16 tokens each). Main kernel: one block per
// (bucket, half); processes 8 tokens per pass with wa chunks staged in LDS.
// Weight reads amortize 8x in-block and stay L2-hot per bucket. Output is
// exclusively owned (each token in exactly one bucket) -> no atomics.
//
// ws layout (ints): [0,256) cnt | [256,512) off | [512,768) cur | [768,+4096) list

#define T_TOKENS 4096
#define NDIM     2048
#define RANK     16
#define NPAIR    256
#define CH       2      // grid chunks per bucket
#define TBB      8      // tokens per sub-batch
#define CHK      256    // K-chunk in floats
#define CHK4     64     // K-chunk in float4
#define PADW     65     // LDS row stride in float4 (64 + 1 pad)

__global__ __launch_bounds__(256) void k_zero(int* wsI) {
    wsI[threadIdx.x] = 0;
}

__global__ __launch_bounds__(256) void k_count(const int* __restrict__ idxs, int* wsI) {
    const int t = blockIdx.x * 256 + threadIdx.x;
    const int pid = idxs[2 * t] * 16 + idxs[2 * t + 1];
    atomicAdd(&wsI[pid], 1);
}

__global__ __launch_bounds__(256) void k_scan(int* wsI) {
    __shared__ int s[256];
    const int tid = threadIdx.x;
    const int v = wsI[tid];
    s[tid] = v;
    __syncthreads();
    for (int d = 1; d < 256; d <<= 1) {
        int add = (tid >= d) ? s[tid - d] : 0;
        __syncthreads();
        s[tid] += add;
        __syncthreads();
    }
    const int excl = s[tid] - v;
    wsI[256 + tid] = excl;   // off
    wsI[512 + tid] = excl;   // cur
}

__global__ __launch_bounds__(256) void k_scatter(const int* __restrict__ idxs, int* wsI) {
    const int t = blockIdx.x * 256 + threadIdx.x;
    const int pid = idxs[2 * t] * 16 + idxs[2 * t + 1];
    const int pos = atomicAdd(&wsI[512 + pid], 1);
    wsI[768 + pos] = t;
}

__global__ __launch_bounds__(256) void moe_main(
    const float* __restrict__ x,        // [T, 2048]
    const float* __restrict__ routing,  // [T, 2]
    const float* __restrict__ wa,       // [16, 16, 2048]
    const float* __restrict__ wb,       // [16, 2048, 16]
    const int*   __restrict__ wsI,
    float* __restrict__ out)            // [T, 2048]
{
    const int pid = blockIdx.y;
    const int n   = wsI[pid];
    if (n == 0) return;
    const int base  = wsI[256 + pid];
    const int chunk = blockIdx.x;
    const int i_beg = base + (chunk * n) / CH;
    const int i_end = base + ((chunk + 1) * n) / CH;
    if (i_beg >= i_end) return;
    const int* list = wsI + 768;
    const int e0 = pid >> 4, e1 = pid & 15;

    __shared__ float4 was[32 * PADW];   // 32 (expert,rank) rows x 64 f4 (+pad)  ~33 KB
    __shared__ float4 xs [TBB * PADW];  // 8 token rows x 64 f4 (+pad)           ~8 KB
    __shared__ float  alds[TBB * 32];   // silu'd activations                     1 KB
    __shared__ int    tl[TBB];

    const int tid   = threadIdx.x;
    const int t_loc = tid >> 5;   // 0..7
    const int p     = tid & 31;   // pair index (k = p>>4, r = p&15)

    const float4* wb0 = (const float4*)(wb + (size_t)e0 * NDIM * RANK);
    const float4* wb1 = (const float4*)(wb + (size_t)e1 * NDIM * RANK);

    for (int sb = i_beg; sb < i_end; sb += TBB) {
        const int m = min(TBB, i_end - sb);
        if (tid < TBB) tl[tid] = list[sb + min(tid, m - 1)];
        __syncthreads();

        // ---- Stage A: a[t_loc][p] = silu(x[t] . wa[e_k, r]) ----
        float4 acc = {0.f, 0.f, 0.f, 0.f};
        for (int c = 0; c < NDIM; c += CHK) {
            // stage wa chunk: rows = 32 (expert,rank) pairs, coalesced 1 KB/wave
            #pragma unroll
            for (int q = 0; q < 8; q++) {
                const int idx = tid + 256 * q;
                const int row = idx >> 6, j4 = idx & 63;
                const int ee  = (row >= 16) ? e1 : e0;
                const int rr  = row & 15;
                was[row * PADW + j4] =
                    *(const float4*)(wa + ((size_t)(ee * RANK + rr)) * NDIM + c + 4 * j4);
            }
            // stage x chunk for the 8 tokens
            #pragma unroll
            for (int q = 0; q < 2; q++) {
                const int idx = tid + 256 * q;
                const int tt = idx >> 6, j4 = idx & 63;
                xs[tt * PADW + j4] =
                    *(const float4*)(x + (size_t)tl[tt] * NDIM + c + 4 * j4);
            }
            __syncthreads();
            #pragma unroll 8
            for (int j4 = 0; j4 < CHK4; j4++) {
                const float4 w  = was[p * PADW + j4];
                const float4 xv = xs[t_loc * PADW + j4];
                acc.x += w.x * xv.x; acc.y += w.y * xv.y;
                acc.z += w.z * xv.z; acc.w += w.w * xv.w;
            }
            __syncthreads();
        }
        float a = (acc.x + acc.y) + (acc.z + acc.w);
        a = a / (1.f + __expf(-a));
        alds[t_loc * 32 + p] = a;
        __syncthreads();

        // ---- Stage B: thread (t_loc, p) covers d = 32*dd + p ----
        if (t_loc < m) {
            const int tok = tl[t_loc];
            const float r0 = routing[tok * 2 + 0];
            const float r1 = routing[tok * 2 + 1];
            float a0[RANK], a1[RANK];
            #pragma unroll
            for (int i = 0; i < RANK; i++) {
                a0[i] = alds[t_loc * 32 + i];
                a1[i] = alds[t_loc * 32 + 16 + i];
            }
            float* orow = out + (size_t)tok * NDIM;
            for (int dd = 0; dd < NDIM / 32; dd++) {
                const int d = dd * 32 + p;
                float s0 = 0.f, s1 = 0.f;
                #pragma unroll
                for (int q = 0; q < 4; q++) {
                    const float4 b0 = wb0[d * 4 + q];
                    const float4 b1 = wb1[d * 4 + q];
                    s0 += b0.x * a0[q*4+0] + b0.y * a0[q*4+1]
                        + b0.z * a0[q*4+2] + b0.w * a0[q*4+3];
                    s1 += b1.x * a1[q*4+0] + b1.y * a1[q*4+1]
                        + b1.z * a1[q*4+2] + b1.w * a1[q*4+3];
                }
                orow[d] = 2.0f * (r0 * s0 + r1 * s1);
            }
        }
        __syncthreads();   // protect tl/was/xs/alds for next sub-batch
    }
}

extern "C" void kernel_launch(void* const* d_in, const int* in_sizes, int n_in,
                              void* d_out, int out_size, void* d_ws, size_t ws_size,
                              hipStream_t stream) {
    const float* x       = (const float*)d_in[0];
    const float* routing = (const float*)d_in[1];
    const int*   idxs    = (const int*)  d_in[2];
    const float* wa      = (const float*)d_in[3];
    const float* wb      = (const float*)d_in[4];
    float*       out     = (float*)d_out;
    int*         wsI     = (int*)d_ws;   // needs ~19.5 KB

    k_zero<<<1, 256, 0, stream>>>(wsI);
    k_count<<<T_TOKENS / 256, 256, 0, stream>>>(idxs, wsI);
    k_scan<<<1, 256, 0, stream>>>(wsI);
    k_scatter<<<T_TOKENS / 256, 256, 0, stream>>>(idxs, wsI);
    dim3 grid(CH, NPAIR);
    moe_main<<<grid, 256, 0, stream>>>(x, routing, wa, wb, wsI, out);
}

// Round 4
// 189.392 us; speedup vs baseline: 1.3383x; 1.3383x over previous
//
#include <hip/hip_runtime.h>
#include <hip/hip_bf16.h>

// SparseLoRAMoE: out[t,d] = 2 * sum_k routing[t,k] *
//                 sum_r silu(dot(x[t,:], w_a[e_k,r,:])) * w_b[e_k,d,r]
// B=2,S=2048 -> 4096 tokens; D_IN=D_OUT=2048; E=16; R=16; K=2. fp32.
//
// Round 4: pair-bucketed (kept from R3 - it fixed HBM traffic), but:
//  - fused A+B in ONE kernel, 3 launches total (was 5)
//  - Stage A: no LDS staging; each wave owns 8 wa rows, lanes along K,
//    16 independent coalesced f4 loads per 256-float window into 64
//    register accumulators; single 63-shuffle butterfly transpose-reduce.
//  - Stage B: wb rows in registers (16 f4/thread, coalesced 64B rows),
//    acts broadcast from 1 KB LDS. One barrier in the whole kernel.

#define NDIM   2048
#define RANK   16
#define NPAIR  256
#define CAP    64      // max tokens per pair bucket (Poisson(16), P(>64)~1e-19)
#define SLDS   36      // acts LDS row stride (floats, 16B-aligned, bank-spread)

__device__ __forceinline__ float silu(float v) {
    return v / (1.f + __expf(-v));
}

// ws layout (ints): [0,256) cnt | [256, 256+256*64) per-bucket token lists
__global__ __launch_bounds__(256) void k_init(int* wsI) {
    wsI[threadIdx.x] = 0;
}

__global__ __launch_bounds__(256) void k_scatter(const int* __restrict__ idxs, int* wsI) {
    const int t = blockIdx.x * 256 + threadIdx.x;
    const int pid = idxs[2 * t] * 16 + idxs[2 * t + 1];
    const int pos = atomicAdd(&wsI[pid], 1);
    if (pos < CAP) wsI[256 + pid * CAP + pos] = t;
}

__global__ __launch_bounds__(256, 2) void moe_fused(
    const float* __restrict__ x,        // [T, 2048]
    const float* __restrict__ routing,  // [T, 2]
    const float* __restrict__ wa,       // [16, 16, 2048]
    const float* __restrict__ wb,       // [16, 2048, 16]
    const int*   __restrict__ wsI,
    float* __restrict__ out)            // [T, 2048]
{
    const int pid = blockIdx.y;
    int n = wsI[pid];
    if (n > CAP) n = CAP;
    const int sb = blockIdx.x * 8;      // token offset within bucket
    if (sb >= n) return;
    const int m = min(8, n - sb);
    const int* list = wsI + 256 + pid * CAP + sb;
    const int e0 = pid >> 4, e1 = pid & 15;

    __shared__ float as[8 * SLDS];      // scaled silu activations [tok][32]
    __shared__ int   tl[8];

    const int tid  = threadIdx.x;
    const int wave = tid >> 6;
    const int lane = tid & 63;

    if (tid < 8) tl[tid] = list[min(tid, m - 1)];
    __syncthreads();

    // ================= Stage A =================
    // wave owns pairs p = wave*8 + p4; k = wave>>1; ranks rbase..rbase+7
    const int e     = (wave >= 2) ? e1 : e0;
    const int rbase = (wave & 1) * 8;

    const float* xrow[8];
    const float* wrow[8];
    #pragma unroll
    for (int tt = 0; tt < 8; tt++) xrow[tt] = x + (size_t)tl[tt] * NDIM;
    #pragma unroll
    for (int p4 = 0; p4 < 8; p4++)
        wrow[p4] = wa + ((size_t)e * RANK + rbase + p4) * NDIM;

    float v[64];
    #pragma unroll
    for (int j = 0; j < 64; j++) v[j] = 0.f;

    for (int w = 0; w < 8; w++) {           // 8 windows of 256 floats
        const int off = w * 256 + lane * 4;
        float4 wv[8], xv[8];
        #pragma unroll
        for (int p4 = 0; p4 < 8; p4++) wv[p4] = *(const float4*)(wrow[p4] + off);
        #pragma unroll
        for (int tt = 0; tt < 8; tt++) xv[tt] = *(const float4*)(xrow[tt] + off);
        #pragma unroll
        for (int p4 = 0; p4 < 8; p4++) {
            #pragma unroll
            for (int tt = 0; tt < 8; tt++) {
                v[p4 * 8 + tt] += wv[p4].x * xv[tt].x + wv[p4].y * xv[tt].y
                                + wv[p4].z * xv[tt].z + wv[p4].w * xv[tt].w;
            }
        }
    }

    // butterfly transpose-reduce: lane L ends holding total of v[L]
    #pragma unroll
    for (int s = 0; s < 6; s++) {
        const int o = 32 >> s;
        const bool up = (lane & o) != 0;
        #pragma unroll
        for (int j = 0; j < (32 >> s); j++) {
            const float send = up ? v[j] : v[j + (32 >> s)];
            const float got  = __shfl_xor(send, o);
            v[j] = (up ? v[j + (32 >> s)] : v[j]) + got;
        }
    }

    {
        const int p4 = lane >> 3;           // pair-local 0..7
        const int tt = lane & 7;            // token-local 0..7
        const int tok = tl[tt];
        const int k   = wave >> 1;
        float a = silu(v[0]) * 2.f * routing[tok * 2 + k];
        as[tt * SLDS + wave * 8 + p4] = a;  // col p = wave*8+p4 in [0,32)
    }
    __syncthreads();

    // ================= Stage B =================
    const float* wb0 = wb + (size_t)e0 * NDIM * RANK;
    const float* wb1 = wb + (size_t)e1 * NDIM * RANK;

    #pragma unroll 1
    for (int jj = 0; jj < 4; jj++) {
        const int d0 = tid + 512 * jj;
        const int d1 = d0 + 256;
        float4 c00[4], c01[4], c10[4], c11[4];
        #pragma unroll
        for (int q = 0; q < 4; q++) {
            c00[q] = *(const float4*)(wb0 + (size_t)d0 * RANK + 4 * q);
            c01[q] = *(const float4*)(wb0 + (size_t)d1 * RANK + 4 * q);
            c10[q] = *(const float4*)(wb1 + (size_t)d0 * RANK + 4 * q);
            c11[q] = *(const float4*)(wb1 + (size_t)d1 * RANK + 4 * q);
        }
        for (int t2 = 0; t2 < m; t2++) {
            const float* ap = as + t2 * SLDS;
            float s0 = 0.f, s1 = 0.f;
            #pragma unroll
            for (int q = 0; q < 4; q++) {
                const float4 a0 = *(const float4*)(ap + 4 * q);
                const float4 a1 = *(const float4*)(ap + RANK + 4 * q);
                s0 += c00[q].x * a0.x + c00[q].y * a0.y
                    + c00[q].z * a0.z + c00[q].w * a0.w
                    + c10[q].x * a1.x + c10[q].y * a1.y
                    + c10[q].z * a1.z + c10[q].w * a1.w;
                s1 += c01[q].x * a0.x + c01[q].y * a0.y
                    + c01[q].z * a0.z + c01[q].w * a0.w
                    + c11[q].x * a1.x + c11[q].y * a1.y
                    + c11[q].z * a1.z + c11[q].w * a1.w;
            }
            const int tok2 = tl[t2];
            out[(size_t)tok2 * NDIM + d0] = s0;
            out[(size_t)tok2 * NDIM + d1] = s1;
        }
    }
}

extern "C" void kernel_launch(void* const* d_in, const int* in_sizes, int n_in,
                              void* d_out, int out_size, void* d_ws, size_t ws_size,
                              hipStream_t stream) {
    const float* x       = (const float*)d_in[0];
    const float* routing = (const float*)d_in[1];
    const int*   idxs    = (const int*)  d_in[2];
    const float* wa      = (const float*)d_in[3];
    const float* wb      = (const float*)d_in[4];
    float*       out     = (float*)d_out;
    int*         wsI     = (int*)d_ws;   // needs 256 + 256*64 ints ~ 66 KB

    k_init<<<1, 256, 0, stream>>>(wsI);
    k_scatter<<<4096 / 256, 256, 0, stream>>>(idxs, wsI);
    dim3 grid(CAP / 8, NPAIR);           // 8 slots x 256 buckets
    moe_fused<<<grid, 256, 0, stream>>>(x, routing, wa, wb, wsI, out);
}